// Round 1
// baseline (582.184 us; speedup 1.0000x reference)
//
#include <hip/hip_runtime.h>

// ---------------------------------------------------------------------------
// FP_SA: fused point-transformer block, MI355X bf16 MFMA implementation.
// Layout convention: all activations token-major [tok, ch] bf16 in workspace.
// MFMA 16x16x32 bf16: A lane(m=l&15, k=(l>>4)*8+j), B lane(n=l&15, same k),
// C lane(col=l&15, row=(l>>4)*4+reg)  [per m89-verified layout].
// ---------------------------------------------------------------------------

typedef float f32x4 __attribute__((ext_vector_type(4)));
typedef __bf16 bf16x8 __attribute__((ext_vector_type(8)));
typedef __bf16 bf16x4 __attribute__((ext_vector_type(4)));

#define MFMA16(a, b, c) __builtin_amdgcn_mfma_f32_16x16x32_bf16((a), (b), (c), 0, 0, 0)

// ---------------- prep: weights -> bf16, zero KV/Ksum ----------------------
__global__ __launch_bounds__(256) void prep_weights_kernel(
    const float* __restrict__ s0, const float* __restrict__ s1,
    const float* __restrict__ s2, const float* __restrict__ s3,
    const float* __restrict__ s4, const float* __restrict__ s5,
    const float* __restrict__ s6,
    __bf16* __restrict__ d0, __bf16* __restrict__ d1, __bf16* __restrict__ d2,
    __bf16* __restrict__ d3, __bf16* __restrict__ d4, __bf16* __restrict__ d5,
    __bf16* __restrict__ d6, float* __restrict__ zbase)
{
    int idx = blockIdx.x * 256 + threadIdx.x;
    if (idx < 327680) {                 // 5 x 65536: q_w, k_w, v_w, merge_w, pos_w2
        int seg = idx >> 16, off = idx & 65535;
        const float* s = (seg == 0) ? s0 : (seg == 1) ? s1 : (seg == 2) ? s2 : (seg == 3) ? s3 : s4;
        __bf16* d = (seg == 0) ? d0 : (seg == 1) ? d1 : (seg == 2) ? d2 : (seg == 3) ? d3 : d4;
        d[off] = (__bf16)s[off];
    } else if (idx < 589824) {          // mlp_w1: 262144
        int off = idx - 327680; d5[off] = (__bf16)s5[off];
    } else if (idx < 720896) {          // mlp_w2: 131072
        int off = idx - 589824; d6[off] = (__bf16)s6[off];
    } else if (idx < 754688) {          // zero KV (32768 f32) + Ksum (1024 f32)
        zbase[idx - 720896] = 0.f;
    }
}

// ---------------- pos-MLP hidden: relu(xyz2 @ w1^T + b1), token-major ------
__global__ __launch_bounds__(256) void pos_hidden_kernel(
    const float* __restrict__ xyz2, const float* __restrict__ pw1,
    const float* __restrict__ pb1, __bf16* __restrict__ Hid)
{
    int bid = blockIdx.x;               // one block per (b, s)
    int b = bid >> 14, s = bid & 16383, j = threadIdx.x;
    const float* xz = xyz2 + ((size_t)b * 16384 + s) * 3;
    float x = xz[0], y = xz[1], z = xz[2];
    float h = fmaf(x, pw1[j * 3 + 0], fmaf(y, pw1[j * 3 + 1], fmaf(z, pw1[j * 3 + 2], pb1[j])));
    Hid[((size_t)b * 16384 + s) * 256 + j] = (__bf16)fmaxf(h, 0.f);
}

// ---------------- transpose fp32 [256, T] -> bf16 [T, 256] -----------------
__global__ __launch_bounds__(256) void transpose_cast_kernel(
    const float* __restrict__ In, __bf16* __restrict__ Outb)
{
    const int tid = threadIdx.x;
    const int t0 = blockIdx.x * 64, c0 = blockIdx.y * 64;
    const size_t b = blockIdx.z;
    __shared__ __bf16 tile[64 * 72];    // [t][c], stride 72 (144B, 16B-aligned)
    #pragma unroll
    for (int i = 0; i < 4; ++i) {
        int c = i * 16 + (tid >> 4);
        int t4 = (tid & 15) * 4;
        float4 v = *(const float4*)(In + (b * 256 + c0 + c) * 16384 + t0 + t4);
        tile[(t4 + 0) * 72 + c] = (__bf16)v.x;
        tile[(t4 + 1) * 72 + c] = (__bf16)v.y;
        tile[(t4 + 2) * 72 + c] = (__bf16)v.z;
        tile[(t4 + 3) * 72 + c] = (__bf16)v.w;
    }
    __syncthreads();
    #pragma unroll
    for (int i = 0; i < 2; ++i) {
        int chunk = tid + i * 256;
        int tr = chunk >> 3, c8 = (chunk & 7) * 8;
        bf16x8 v = *(const bf16x8*)(tile + tr * 72 + c8);
        *(bf16x8*)(Outb + (b * 16384 + t0 + tr) * 256 + c0 + c8) = v;
    }
}

// ---------------- generic token-major GEMM: C[tok,ch] = A[tok,:] . W[ch,:] -
enum { EPI_STORE = 0, EPI_ELU = 1, EPI_ADDB = 2, EPI_RELU = 3 };

template <int EPI, bool SPLIT>
__global__ __launch_bounds__(256) void gemm_tok(
    const __bf16* __restrict__ Wg,   // [Cout, K] row-major
    const __bf16* __restrict__ A0,   // [T, 256] (k < 256)
    const __bf16* __restrict__ A1,   // [T, 256] (k >= 256, SPLIT only)
    __bf16* __restrict__ Outg,       // [T, Cout]
    const float* __restrict__ bias,  // EPI_ADDB
    const __bf16* __restrict__ addg, // EPI_ADDB residual [T, 256]
    int K, int Cout)
{
    const int tid = threadIdx.x, w = tid >> 6, l = tid & 63, lm = l & 15;
    const int gm0 = blockIdx.x * 128, gn0 = blockIdx.y * 128;
    const size_t b = blockIdx.z;
    const __bf16* A0b = A0 + b * 16384 * (size_t)256;
    const __bf16* A1b = SPLIT ? (A1 + b * 16384 * (size_t)256) : nullptr;
    __bf16* Outb = Outg + b * 16384 * (size_t)Cout;
    const __bf16* addb = (EPI == EPI_ADDB) ? (addg + b * 16384 * (size_t)256) : nullptr;

    __shared__ __bf16 Alds[128 * 40];
    __shared__ __bf16 Wlds[128 * 40];

    f32x4 acc[4][4];
    #pragma unroll
    for (int i = 0; i < 4; ++i)
        #pragma unroll
        for (int j = 0; j < 4; ++j) acc[i][j] = (f32x4){0.f, 0.f, 0.f, 0.f};

    const int wm = (w >> 1) * 64, wn = (w & 1) * 64;
    const int srow = tid >> 2, scol = (tid & 3) * 8;
    const int koff = (l >> 4) * 8;

    for (int ks = 0; ks < K; ks += 32) {
        const __bf16* As; int kk;
        if (SPLIT && ks >= 256) { As = A1b; kk = ks - 256; } else { As = A0b; kk = ks; }
        int4 a0 = *(const int4*)(As + (size_t)(gm0 + srow) * 256 + kk + scol);
        int4 a1 = *(const int4*)(As + (size_t)(gm0 + srow + 64) * 256 + kk + scol);
        int4 w0 = *(const int4*)(Wg + (size_t)(gn0 + srow) * K + ks + scol);
        int4 w1 = *(const int4*)(Wg + (size_t)(gn0 + srow + 64) * K + ks + scol);
        __syncthreads();
        *(int4*)(Alds + srow * 40 + scol) = a0;
        *(int4*)(Alds + (srow + 64) * 40 + scol) = a1;
        *(int4*)(Wlds + srow * 40 + scol) = w0;
        *(int4*)(Wlds + (srow + 64) * 40 + scol) = w1;
        __syncthreads();
        bf16x8 af[4], bfr[4];
        #pragma unroll
        for (int mf = 0; mf < 4; ++mf)
            af[mf] = *(const bf16x8*)(Alds + (wm + mf * 16 + lm) * 40 + koff);
        #pragma unroll
        for (int nf = 0; nf < 4; ++nf)
            bfr[nf] = *(const bf16x8*)(Wlds + (wn + nf * 16 + lm) * 40 + koff);
        #pragma unroll
        for (int mf = 0; mf < 4; ++mf)
            #pragma unroll
            for (int nf = 0; nf < 4; ++nf)
                acc[mf][nf] = MFMA16(af[mf], bfr[nf], acc[mf][nf]);
    }

    const int r0 = (l >> 4) * 4;
    #pragma unroll
    for (int mf = 0; mf < 4; ++mf) {
        #pragma unroll
        for (int nf = 0; nf < 4; ++nf) {
            int tok = gm0 + wm + mf * 16 + r0;
            int ch  = gn0 + wn + nf * 16 + lm;
            #pragma unroll
            for (int r = 0; r < 4; ++r) {
                float v = acc[mf][nf][r];
                if (EPI == EPI_ELU)  v = (v > 0.f) ? (v + 1.f) : __expf(v);  // elu(x)+1
                if (EPI == EPI_RELU) v = fmaxf(v, 0.f);
                if (EPI == EPI_ADDB) v = v + bias[ch] + (float)addb[(size_t)(tok + r) * 256 + ch];
                Outb[(size_t)(tok + r) * Cout + ch] = (__bf16)v;
            }
        }
    }
}

// ---------------- Ksum[b, ch] = sum_s K[b, s, ch] --------------------------
__global__ __launch_bounds__(256) void ksum_kernel(
    const __bf16* __restrict__ Kb, float* __restrict__ KS)
{
    int b = blockIdx.y, s0 = blockIdx.x * 256, c = threadIdx.x;
    float s = 0.f;
    for (int i = 0; i < 256; ++i)
        s += (float)Kb[((size_t)b * 16384 + s0 + i) * 256 + c];
    atomicAdd(&KS[b * 256 + c], s);
}

// ---------------- KV[b,h,d,e] = sum_s K[s,hd] * v[s,he] --------------------
__global__ __launch_bounds__(256) void kv_kernel(
    const __bf16* __restrict__ Kb, const __bf16* __restrict__ Vb,
    float* __restrict__ KVg)
{
    const int tid = threadIdx.x, w = tid >> 6, l = tid & 63, lm = l & 15;
    const int sc = blockIdx.x, h = blockIdx.y, b = blockIdx.z;
    __shared__ __bf16 kT[32 * 264];   // [d][s] transposed
    __shared__ __bf16 vT[32 * 264];   // [e][s] transposed
    __shared__ float red[4 * 32 * 32];

    f32x4 acc[2][2];
    #pragma unroll
    for (int i = 0; i < 2; ++i)
        #pragma unroll
        for (int j = 0; j < 2; ++j) acc[i][j] = (f32x4){0.f, 0.f, 0.f, 0.f};

    const int koff = (l >> 4) * 8, r0 = (l >> 4) * 4;
    for (int sub = 0; sub < 4; ++sub) {
        int s0 = sc * 1024 + sub * 256;
        __syncthreads();   // protect previous iteration's fragment reads
        for (int pass = 0; pass < 8; ++pass) {
            int sl = pass * 32 + (tid >> 3);
            int c4 = (tid & 7) * 4;
            bf16x4 kv4 = *(const bf16x4*)(Kb + ((size_t)b * 16384 + s0 + sl) * 256 + h * 32 + c4);
            bf16x4 vv4 = *(const bf16x4*)(Vb + ((size_t)b * 16384 + s0 + sl) * 256 + h * 32 + c4);
            #pragma unroll
            for (int i = 0; i < 4; ++i) {
                kT[(c4 + i) * 264 + sl] = kv4[i];
                vT[(c4 + i) * 264 + sl] = vv4[i];
            }
        }
        __syncthreads();
        #pragma unroll
        for (int kq = 0; kq < 2; ++kq) {   // wave w covers s in [w*64, w*64+64)
            int sb = w * 64 + kq * 32;
            bf16x8 af[2], bfr[2];
            #pragma unroll
            for (int mf = 0; mf < 2; ++mf)
                af[mf] = *(const bf16x8*)(kT + (mf * 16 + lm) * 264 + sb + koff);
            #pragma unroll
            for (int nf = 0; nf < 2; ++nf)
                bfr[nf] = *(const bf16x8*)(vT + (nf * 16 + lm) * 264 + sb + koff);
            #pragma unroll
            for (int mf = 0; mf < 2; ++mf)
                #pragma unroll
                for (int nf = 0; nf < 2; ++nf)
                    acc[mf][nf] = MFMA16(af[mf], bfr[nf], acc[mf][nf]);
        }
    }
    #pragma unroll
    for (int mf = 0; mf < 2; ++mf)
        #pragma unroll
        for (int nf = 0; nf < 2; ++nf)
            #pragma unroll
            for (int r = 0; r < 4; ++r) {
                int d = mf * 16 + r0 + r, e = nf * 16 + lm;
                red[w * 1024 + d * 32 + e] = acc[mf][nf][r];
            }
    __syncthreads();
    #pragma unroll
    for (int i = 0; i < 4; ++i) {
        int idx = tid + i * 256;
        float s = red[idx] + red[1024 + idx] + red[2048 + idx] + red[3072 + idx];
        atomicAdd(&KVg[((size_t)(b * 8 + h)) * 1024 + idx], s);
    }
}

// ------- attention apply + merge GEMM + LayerNorm1 -> msg1 bf16 ------------
__global__ __launch_bounds__(256) void attn_merge_ln1(
    const __bf16* __restrict__ Qb, const float* __restrict__ KVg,
    const float* __restrict__ KSg, const __bf16* __restrict__ Wm,
    const float* __restrict__ g1, const float* __restrict__ b1,
    __bf16* __restrict__ Msg1)
{
    const int tid = threadIdx.x, w = tid >> 6, l = tid & 63, lm = l & 15;
    const int b = blockIdx.y, tok0 = blockIdx.x * 64;
    __shared__ __bf16 q_lds[64 * 264];
    __shared__ __bf16 msg_lds[64 * 264];
    __shared__ __bf16 kvT[8 * 32 * 40];   // [h][e][d]
    __shared__ __bf16 wtile[256 * 40];
    __shared__ float ks_lds[256], z_lds[64 * 8], g_lds[256], bl_lds[256];

    const __bf16* Qrow = Qb + ((size_t)b * 16384 + tok0) * 256;
    #pragma unroll
    for (int i = 0; i < 8; ++i) {
        int c = tid + i * 256, row = c >> 5, col8 = (c & 31) * 8;
        *(int4*)(q_lds + row * 264 + col8) = *(const int4*)(Qrow + row * 256 + col8);
    }
    const float* KVb = KVg + (size_t)b * 8192;
    #pragma unroll
    for (int i = 0; i < 32; ++i) {
        int idx = tid + i * 256;
        int h = idx >> 10, d = (idx >> 5) & 31, e = idx & 31;
        kvT[(h * 32 + e) * 40 + d] = (__bf16)KVb[idx];
    }
    ks_lds[tid & 255] = KSg[b * 256 + (tid & 255)];
    g_lds[tid & 255] = g1[tid & 255];
    bl_lds[tid & 255] = b1[tid & 255];
    __syncthreads();

    // Z[tok, h] = 1 / (sum_d Q[tok, hd] * Ksum[hd] + eps)
    #pragma unroll
    for (int i = 0; i < 2; ++i) {
        int p = tid + i * 256, tok = p >> 3, h = p & 7;
        float s = 0.f;
        #pragma unroll
        for (int d = 0; d < 32; ++d)
            s += (float)q_lds[tok * 264 + h * 32 + d] * ks_lds[h * 32 + d];
        z_lds[tok * 8 + h] = 1.f / (s + 1e-6f);
    }
    __syncthreads();

    // msg[tok, he] = (sum_d Q[tok,hd] * KV[h,d,e]) * Z[tok,h]
    const int koff = (l >> 4) * 8, r0 = (l >> 4) * 4;
    f32x4 z4 = (f32x4){0.f, 0.f, 0.f, 0.f};
    #pragma unroll
    for (int h = 0; h < 8; ++h) {
        bf16x8 af = *(const bf16x8*)(q_lds + (w * 16 + lm) * 264 + h * 32 + koff);
        #pragma unroll
        for (int nf = 0; nf < 2; ++nf) {
            bf16x8 bv = *(const bf16x8*)(kvT + (h * 32 + nf * 16 + lm) * 40 + koff);
            f32x4 m = MFMA16(af, bv, z4);
            #pragma unroll
            for (int r = 0; r < 4; ++r) {
                int tok = w * 16 + r0 + r;
                float v = m[r] * z_lds[tok * 8 + h];
                msg_lds[tok * 264 + h * 32 + nf * 16 + lm] = (__bf16)v;
            }
        }
    }
    __syncthreads();

    // merged[tok, c] = sum_e msg[tok, e] * merge_w[c, e]; then LN1
    f32x4 acc[16];
    #pragma unroll
    for (int i = 0; i < 16; ++i) acc[i] = (f32x4){0.f, 0.f, 0.f, 0.f};
    for (int ks = 0; ks < 256; ks += 32) {
        int4 wreg[4];
        #pragma unroll
        for (int i = 0; i < 4; ++i) {
            int c = tid + i * 256, row = c >> 2, col8 = (c & 3) * 8;
            wreg[i] = *(const int4*)(Wm + (size_t)row * 256 + ks + col8);
        }
        __syncthreads();
        #pragma unroll
        for (int i = 0; i < 4; ++i) {
            int c = tid + i * 256, row = c >> 2, col8 = (c & 3) * 8;
            *(int4*)(wtile + row * 40 + col8) = wreg[i];
        }
        __syncthreads();
        bf16x8 af = *(const bf16x8*)(msg_lds + (w * 16 + lm) * 264 + ks + koff);
        #pragma unroll
        for (int nf = 0; nf < 16; ++nf) {
            bf16x8 bv = *(const bf16x8*)(wtile + (nf * 16 + lm) * 40 + koff);
            acc[nf] = MFMA16(af, bv, acc[nf]);
        }
    }
    #pragma unroll
    for (int r = 0; r < 4; ++r) {
        float s1 = 0.f, s2 = 0.f;
        #pragma unroll
        for (int nf = 0; nf < 16; ++nf) { float v = acc[nf][r]; s1 += v; s2 += v * v; }
        for (int m = 1; m < 16; m <<= 1) { s1 += __shfl_xor(s1, m, 64); s2 += __shfl_xor(s2, m, 64); }
        float mu = s1 * (1.f / 256.f);
        float rstd = rsqrtf(s2 * (1.f / 256.f) - mu * mu + 1e-5f);
        int tok = tok0 + w * 16 + r0 + r;
        #pragma unroll
        for (int nf = 0; nf < 16; ++nf) {
            int c = nf * 16 + lm;
            float y = (acc[nf][r] - mu) * rstd * g_lds[c] + bl_lds[c];
            Msg1[((size_t)b * 16384 + tok) * 256 + c] = (__bf16)y;
        }
    }
}

// ------- mlp2 GEMM + LayerNorm2 + transposed fp32 store --------------------
__global__ __launch_bounds__(256) void mlp2_ln2(
    const __bf16* __restrict__ H1g, const __bf16* __restrict__ W2g,
    const float* __restrict__ g2, const float* __restrict__ b2,
    float* __restrict__ Outg)
{
    const int tid = threadIdx.x, w = tid >> 6, l = tid & 63, lm = l & 15;
    const int b = blockIdx.y, tok0 = blockIdx.x * 64;
    __shared__ __bf16 atile[64 * 40];
    __shared__ __bf16 wtile[256 * 40];
    __shared__ float out_lds[64 * 257];
    __shared__ float g_lds[256], bl_lds[256];
    g_lds[tid & 255] = g2[tid & 255];
    bl_lds[tid & 255] = b2[tid & 255];

    const __bf16* Hrow = H1g + ((size_t)b * 16384 + tok0) * 512;
    f32x4 acc[16];
    #pragma unroll
    for (int i = 0; i < 16; ++i) acc[i] = (f32x4){0.f, 0.f, 0.f, 0.f};
    const int koff = (l >> 4) * 8, r0 = (l >> 4) * 4;
    const int arow = tid >> 2, acol = (tid & 3) * 8;

    for (int ks = 0; ks < 512; ks += 32) {
        int4 areg = *(const int4*)(Hrow + (size_t)arow * 512 + ks + acol);
        int4 wreg[4];
        #pragma unroll
        for (int i = 0; i < 4; ++i) {
            int c = tid + i * 256, row = c >> 2, col8 = (c & 3) * 8;
            wreg[i] = *(const int4*)(W2g + (size_t)row * 512 + ks + col8);
        }
        __syncthreads();
        *(int4*)(atile + arow * 40 + acol) = areg;
        #pragma unroll
        for (int i = 0; i < 4; ++i) {
            int c = tid + i * 256, row = c >> 2, col8 = (c & 3) * 8;
            *(int4*)(wtile + row * 40 + col8) = wreg[i];
        }
        __syncthreads();
        bf16x8 af = *(const bf16x8*)(atile + (w * 16 + lm) * 40 + koff);
        #pragma unroll
        for (int nf = 0; nf < 16; ++nf) {
            bf16x8 bv = *(const bf16x8*)(wtile + (nf * 16 + lm) * 40 + koff);
            acc[nf] = MFMA16(af, bv, acc[nf]);
        }
    }
    #pragma unroll
    for (int r = 0; r < 4; ++r) {
        float s1 = 0.f, s2 = 0.f;
        #pragma unroll
        for (int nf = 0; nf < 16; ++nf) { float v = acc[nf][r]; s1 += v; s2 += v * v; }
        for (int m = 1; m < 16; m <<= 1) { s1 += __shfl_xor(s1, m, 64); s2 += __shfl_xor(s2, m, 64); }
        float mu = s1 * (1.f / 256.f);
        float rstd = rsqrtf(s2 * (1.f / 256.f) - mu * mu + 1e-5f);
        #pragma unroll
        for (int nf = 0; nf < 16; ++nf) {
            int c = nf * 16 + lm;
            out_lds[(w * 16 + r0 + r) * 257 + c] = (acc[nf][r] - mu) * rstd * g_lds[c] + bl_lds[c];
        }
    }
    __syncthreads();
    for (int cb = 0; cb < 64; ++cb) {   // coalesced transposed store [b][c][tok]
        int c = cb * 4 + w;
        Outg[((size_t)b * 256 + c) * 16384 + tok0 + l] = out_lds[l * 257 + c];
    }
}

// ---------------------------------------------------------------------------
extern "C" void kernel_launch(void* const* d_in, const int* in_sizes, int n_in,
                              void* d_out, int out_size, void* d_ws, size_t ws_size,
                              hipStream_t stream) {
    const float* feat1   = (const float*)d_in[0];
    const float* feat2   = (const float*)d_in[2];
    const float* xyz2    = (const float*)d_in[3];
    const float* pos_w1  = (const float*)d_in[4];
    const float* pos_b1  = (const float*)d_in[5];
    const float* pos_w2  = (const float*)d_in[6];
    const float* pos_b2  = (const float*)d_in[7];
    const float* q_w     = (const float*)d_in[8];
    const float* k_w     = (const float*)d_in[9];
    const float* v_w     = (const float*)d_in[10];
    const float* merge_w = (const float*)d_in[11];
    const float* mlp_w1  = (const float*)d_in[12];
    const float* mlp_w2  = (const float*)d_in[13];
    const float* ln1_g   = (const float*)d_in[14];
    const float* ln1_b   = (const float*)d_in[15];
    const float* ln2_g   = (const float*)d_in[16];
    const float* ln2_b   = (const float*)d_in[17];
    float* outp = (float*)d_out;

    char* ws = (char*)d_ws;
    size_t off = 0;
    auto alloc = [&](size_t bytes) { char* p = ws + off; off += (bytes + 255) & ~(size_t)255; return p; };
    const size_t ACT = (size_t)4 * 16384 * 256 * 2;   // 33.55 MB per bf16 activation
    __bf16* WQ  = (__bf16*)alloc(65536 * 2);
    __bf16* WK  = (__bf16*)alloc(65536 * 2);
    __bf16* WV  = (__bf16*)alloc(65536 * 2);
    __bf16* WM  = (__bf16*)alloc(65536 * 2);
    __bf16* WP2 = (__bf16*)alloc(65536 * 2);
    __bf16* W1  = (__bf16*)alloc(262144 * 2);
    __bf16* W2  = (__bf16*)alloc(131072 * 2);
    float*  KV  = (float*)alloc(4 * 8 * 32 * 32 * 4);  // zeroed each call
    float*  KS  = (float*)alloc(4 * 256 * 4);          // (contiguous with KV)
    __bf16* F1T = (__bf16*)alloc(ACT);
    __bf16* HID = (__bf16*)alloc(ACT);   // later reused (with F2T) as H1 [tok,512]
    __bf16* F2T = (__bf16*)alloc(ACT);   // must be contiguous after HID
    __bf16* F2P = (__bf16*)alloc(ACT);   // later reused as MSG1
    __bf16* KB  = (__bf16*)alloc(ACT);
    __bf16* VB  = (__bf16*)alloc(ACT);
    __bf16* QB  = (__bf16*)alloc(ACT);
    __bf16* H1   = HID;   // 67.1 MB spanning HID+F2T
    __bf16* MSG1 = F2P;
    if (ws_size < off) return;   // insufficient scratch: fail loudly (output stays poisoned)

    // 1. weights -> bf16, zero KV/Ksum
    prep_weights_kernel<<<2948, 256, 0, stream>>>(q_w, k_w, v_w, merge_w, pos_w2,
                                                  mlp_w1, mlp_w2,
                                                  WQ, WK, WV, WM, WP2, W1, W2, KV);
    // 2. pos-MLP hidden
    pos_hidden_kernel<<<65536, 256, 0, stream>>>(xyz2, pos_w1, pos_b1, HID);
    // 3/4. transpose feat1, feat2 to token-major bf16
    transpose_cast_kernel<<<dim3(256, 4, 4), 256, 0, stream>>>(feat1, F1T);
    transpose_cast_kernel<<<dim3(256, 4, 4), 256, 0, stream>>>(feat2, F2T);
    // 5. pos GEMM + bias + residual: F2P = f2 + (hidden @ pos_w2^T + pos_b2)
    gemm_tok<EPI_ADDB, false><<<dim3(128, 2, 4), 256, 0, stream>>>(WP2, HID, nullptr, F2P, pos_b2, F2T, 256, 256);
    // 6. K = elu(f2 @ k_w^T) + 1
    gemm_tok<EPI_ELU, false><<<dim3(128, 2, 4), 256, 0, stream>>>(WK, F2T, nullptr, KB, nullptr, nullptr, 256, 256);
    // 7. v = f2p @ v_w^T
    gemm_tok<EPI_STORE, false><<<dim3(128, 2, 4), 256, 0, stream>>>(WV, F2P, nullptr, VB, nullptr, nullptr, 256, 256);
    // 8. Q = elu(f1 @ q_w^T) + 1
    gemm_tok<EPI_ELU, false><<<dim3(128, 2, 4), 256, 0, stream>>>(WQ, F1T, nullptr, QB, nullptr, nullptr, 256, 256);
    // 9. Ksum
    ksum_kernel<<<dim3(64, 4), 256, 0, stream>>>(KB, KS);
    // 10. KV
    kv_kernel<<<dim3(16, 8, 4), 256, 0, stream>>>(KB, VB, KV);
    // 11. attention apply + merge + LN1 -> msg1
    attn_merge_ln1<<<dim3(256, 4), 256, 0, stream>>>(QB, KV, KS, WM, ln1_g, ln1_b, MSG1);
    // 12. h1 = relu([f1, msg1] @ mlp_w1^T)
    gemm_tok<EPI_RELU, true><<<dim3(128, 4, 4), 256, 0, stream>>>(W1, F1T, MSG1, H1, nullptr, nullptr, 512, 512);
    // 13. out = LN2(h1 @ mlp_w2^T), stored [B, 256, N] fp32
    mlp2_ln2<<<dim3(256, 4), 256, 0, stream>>>(H1, W2, ln2_g, ln2_b, outp);
    (void)in_sizes; (void)n_in; (void)out_size;
}

// Round 2
// 453.844 us; speedup vs baseline: 1.2828x; 1.2828x over previous
//
#include <hip/hip_runtime.h>

// ---------------------------------------------------------------------------
// FP_SA: fused point-transformer block, MI355X bf16 MFMA implementation.
// Token-major [tok, ch] bf16 activations. MFMA 16x16x32 bf16.
// GEMMs use global_load_lds (width 16) into linear LDS tiles (m97 structure).
// ---------------------------------------------------------------------------

typedef float f32x4 __attribute__((ext_vector_type(4)));
typedef __bf16 bf16x8 __attribute__((ext_vector_type(8)));
typedef __bf16 bf16x4 __attribute__((ext_vector_type(4)));

#define MFMA16(a, b, c) __builtin_amdgcn_mfma_f32_16x16x32_bf16((a), (b), (c), 0, 0, 0)

__device__ __forceinline__ void gll16(const __bf16* g, __bf16* l) {
    __builtin_amdgcn_global_load_lds(
        (const __attribute__((address_space(1))) void*)g,
        (__attribute__((address_space(3))) void*)l, 16, 0, 0);
}

// ---------------- prep: weights -> bf16, zero KV/Ksum ----------------------
__global__ __launch_bounds__(256) void prep_weights_kernel(
    const float* __restrict__ s0, const float* __restrict__ s1,
    const float* __restrict__ s2, const float* __restrict__ s3,
    const float* __restrict__ s4, const float* __restrict__ s5,
    const float* __restrict__ s6,
    __bf16* __restrict__ d0, __bf16* __restrict__ d1, __bf16* __restrict__ d2,
    __bf16* __restrict__ d3, __bf16* __restrict__ d4, __bf16* __restrict__ d5,
    __bf16* __restrict__ d6, float* __restrict__ zbase)
{
    int idx = blockIdx.x * 256 + threadIdx.x;
    if (idx < 327680) {                 // 5 x 65536: q_w, k_w, v_w, merge_w, pos_w2
        int seg = idx >> 16, off = idx & 65535;
        const float* s = (seg == 0) ? s0 : (seg == 1) ? s1 : (seg == 2) ? s2 : (seg == 3) ? s3 : s4;
        __bf16* d = (seg == 0) ? d0 : (seg == 1) ? d1 : (seg == 2) ? d2 : (seg == 3) ? d3 : d4;
        d[off] = (__bf16)s[off];
    } else if (idx < 589824) {          // mlp_w1: 262144
        int off = idx - 327680; d5[off] = (__bf16)s5[off];
    } else if (idx < 720896) {          // mlp_w2: 131072
        int off = idx - 589824; d6[off] = (__bf16)s6[off];
    } else if (idx < 754688) {          // zero KV (32768 f32) + Ksum (1024 f32)
        zbase[idx - 720896] = 0.f;
    }
}

// ---------------- pos-MLP hidden: relu(xyz2 @ w1^T + b1), token-major ------
__global__ __launch_bounds__(256) void pos_hidden_kernel(
    const float* __restrict__ xyz2, const float* __restrict__ pw1,
    const float* __restrict__ pb1, __bf16* __restrict__ Hid)
{
    const int tid = threadIdx.x;
    size_t tok = (size_t)blockIdx.x * 8 + (tid >> 5);   // 0..65535
    int c0 = (tid & 31) * 8;
    const float* xz = xyz2 + tok * 3;
    float x = xz[0], y = xz[1], z = xz[2];
    bf16x8 o;
    #pragma unroll
    for (int j = 0; j < 8; ++j) {
        const float* wr = pw1 + (size_t)(c0 + j) * 3;
        float h = fmaf(x, wr[0], fmaf(y, wr[1], fmaf(z, wr[2], pb1[c0 + j])));
        o[j] = (__bf16)fmaxf(h, 0.f);
    }
    *(bf16x8*)(Hid + tok * 256 + c0) = o;
}

// ---------------- transpose fp32 [256, T] -> bf16 [T, 256] -----------------
__global__ __launch_bounds__(256) void transpose_cast_kernel(
    const float* __restrict__ In, __bf16* __restrict__ Outb)
{
    const int tid = threadIdx.x;
    const int t0 = blockIdx.x * 64, c0 = blockIdx.y * 64;
    const size_t b = blockIdx.z;
    __shared__ __bf16 tile[64 * 72];
    #pragma unroll
    for (int i = 0; i < 4; ++i) {
        int c = i * 16 + (tid >> 4);
        int t4 = (tid & 15) * 4;
        float4 v = *(const float4*)(In + (b * 256 + c0 + c) * 16384 + t0 + t4);
        tile[(t4 + 0) * 72 + c] = (__bf16)v.x;
        tile[(t4 + 1) * 72 + c] = (__bf16)v.y;
        tile[(t4 + 2) * 72 + c] = (__bf16)v.z;
        tile[(t4 + 3) * 72 + c] = (__bf16)v.w;
    }
    __syncthreads();
    #pragma unroll
    for (int i = 0; i < 2; ++i) {
        int chunk = tid + i * 256;
        int tr = chunk >> 3, c8 = (chunk & 7) * 8;
        bf16x8 v = *(const bf16x8*)(tile + tr * 72 + c8);
        *(bf16x8*)(Outb + (b * 16384 + t0 + tr) * 256 + c0 + c8) = v;
    }
}

// ---------------- generic token-major GEMM: C[tok,ch] = A[tok,:] . W[ch,:] -
enum { EPI_STORE = 0, EPI_ELU = 1, EPI_ADDB = 2, EPI_RELU = 3, EPI_ELU_KSUM = 4 };

template <int EPI, bool SPLIT>
__global__ __launch_bounds__(256, 2) void gemm_tok(
    const __bf16* __restrict__ Wg,   // [Cout, K] row-major
    const __bf16* __restrict__ A0,   // [T, 256] (k < 256)
    const __bf16* __restrict__ A1,   // [T, 256] (k >= 256, SPLIT only)
    __bf16* __restrict__ Outg,       // [T, Cout]
    const float* __restrict__ bias,  // EPI_ADDB
    const __bf16* __restrict__ addg, // EPI_ADDB residual [T, 256]
    float* __restrict__ KSg,         // EPI_ELU_KSUM: [B, 256] fp32 (pre-zeroed)
    int K, int Cout)
{
    const int tid = threadIdx.x, w = tid >> 6, l = tid & 63, lm = l & 15;
    const int gm0 = blockIdx.x * 128, gn0 = blockIdx.y * 128;
    const size_t b = blockIdx.z;
    const __bf16* A0b = A0 + b * 16384 * (size_t)256;
    const __bf16* A1b = SPLIT ? (A1 + b * 16384 * (size_t)256) : nullptr;
    __bf16* Outb = Outg + b * 16384 * (size_t)Cout;
    const __bf16* addb = (EPI == EPI_ADDB) ? (addg + b * 16384 * (size_t)256) : nullptr;

    __shared__ __bf16 Alds[128 * 32];   // linear: row stride 32 elems
    __shared__ __bf16 Wlds[128 * 32];
    __shared__ float kred[16 * 64];     // only used by EPI_ELU_KSUM

    f32x4 acc[4][4];
    #pragma unroll
    for (int i = 0; i < 4; ++i)
        #pragma unroll
        for (int j = 0; j < 4; ++j) acc[i][j] = (f32x4){0.f, 0.f, 0.f, 0.f};

    const int wm = (w >> 1) * 64, wn = (w & 1) * 64;
    const int srow = tid >> 2, scol = (tid & 3) * 8;  // staging: row within 64-chunk, col
    const int koff = (l >> 4) * 8;
    const int wbase = w * 512;                        // LDS elem base for this wave's gll

    for (int ks = 0; ks < K; ks += 32) {
        const __bf16* As = A0b; int kk = ks;
        if (SPLIT && ks >= 256) { As = A1b; kk = ks - 256; }
        __syncthreads();   // previous iteration's fragment reads done
        gll16(As + (size_t)(gm0 + srow) * 256 + kk + scol,      Alds + wbase);
        gll16(As + (size_t)(gm0 + 64 + srow) * 256 + kk + scol, Alds + 2048 + wbase);
        gll16(Wg + (size_t)(gn0 + srow) * K + ks + scol,        Wlds + wbase);
        gll16(Wg + (size_t)(gn0 + 64 + srow) * K + ks + scol,   Wlds + 2048 + wbase);
        __syncthreads();   // drains vmcnt -> LDS tiles complete
        bf16x8 af[4], wf[4];
        #pragma unroll
        for (int mf = 0; mf < 4; ++mf)
            af[mf] = *(const bf16x8*)(Alds + (wm + mf * 16 + lm) * 32 + koff);
        #pragma unroll
        for (int nf = 0; nf < 4; ++nf)
            wf[nf] = *(const bf16x8*)(Wlds + (wn + nf * 16 + lm) * 32 + koff);
        #pragma unroll
        for (int mf = 0; mf < 4; ++mf)
            #pragma unroll
            for (int nf = 0; nf < 4; ++nf)
                acc[mf][nf] = MFMA16(af[mf], wf[nf], acc[mf][nf]);
    }

    const int r0 = (l >> 4) * 4;
    float kpart[4] = {0.f, 0.f, 0.f, 0.f};
    #pragma unroll
    for (int mf = 0; mf < 4; ++mf) {
        #pragma unroll
        for (int nf = 0; nf < 4; ++nf) {
            int tok = gm0 + wm + mf * 16 + r0;
            int ch  = gn0 + wn + nf * 16 + lm;
            #pragma unroll
            for (int r = 0; r < 4; ++r) {
                float v = acc[mf][nf][r];
                if (EPI == EPI_ELU || EPI == EPI_ELU_KSUM)
                    v = (v > 0.f) ? (v + 1.f) : __expf(v);   // elu(x)+1
                if (EPI == EPI_RELU) v = fmaxf(v, 0.f);
                if (EPI == EPI_ADDB) v = v + bias[ch] + (float)addb[(size_t)(tok + r) * 256 + ch];
                if (EPI == EPI_ELU_KSUM) kpart[nf] += v;
                Outb[(size_t)(tok + r) * Cout + ch] = (__bf16)v;
            }
        }
    }
    if (EPI == EPI_ELU_KSUM) {
        // block-level column reduce, then one atomic per channel
        #pragma unroll
        for (int nf = 0; nf < 4; ++nf)
            kred[(w * 4 + (l >> 4)) * 64 + nf * 16 + lm] = kpart[nf];
        __syncthreads();
        if (tid < 128) {
            int c = tid;                     // channel within 128-tile
            int wsel = (c >= 64) ? 1 : 0;    // waves {wsel, wsel+2} cover this ch range
            float s = 0.f;
            #pragma unroll
            for (int q = 0; q < 4; ++q)
                s += kred[((wsel * 4) + q) * 64 + (c & 63)]
                   + kred[(((wsel + 2) * 4) + q) * 64 + (c & 63)];
            atomicAdd(&KSg[b * 256 + gn0 + c], s);
        }
    }
}

// ---------------- KV[b,h,d,e] = sum_s K[s,hd] * v[s,he] --------------------
__global__ __launch_bounds__(256) void kv_kernel(
    const __bf16* __restrict__ Kb, const __bf16* __restrict__ Vb,
    float* __restrict__ KVg)
{
    const int tid = threadIdx.x, w = tid >> 6, l = tid & 63, lm = l & 15;
    const int sc = blockIdx.x, h = blockIdx.y, b = blockIdx.z;
    __shared__ __bf16 kT[32 * 264];   // [d][s] transposed
    __shared__ __bf16 vT[32 * 264];   // [e][s] transposed
    __shared__ float red[4 * 32 * 32];

    f32x4 acc[2][2];
    #pragma unroll
    for (int i = 0; i < 2; ++i)
        #pragma unroll
        for (int j = 0; j < 2; ++j) acc[i][j] = (f32x4){0.f, 0.f, 0.f, 0.f};

    const int koff = (l >> 4) * 8, r0 = (l >> 4) * 4;
    for (int sub = 0; sub < 4; ++sub) {
        int s0 = sc * 1024 + sub * 256;
        __syncthreads();
        for (int pass = 0; pass < 8; ++pass) {
            int sl = pass * 32 + (tid >> 3);
            int c4 = (tid & 7) * 4;
            bf16x4 kv4 = *(const bf16x4*)(Kb + ((size_t)b * 16384 + s0 + sl) * 256 + h * 32 + c4);
            bf16x4 vv4 = *(const bf16x4*)(Vb + ((size_t)b * 16384 + s0 + sl) * 256 + h * 32 + c4);
            #pragma unroll
            for (int i = 0; i < 4; ++i) {
                kT[(c4 + i) * 264 + sl] = kv4[i];
                vT[(c4 + i) * 264 + sl] = vv4[i];
            }
        }
        __syncthreads();
        #pragma unroll
        for (int kq = 0; kq < 2; ++kq) {
            int sb = w * 64 + kq * 32;
            bf16x8 af[2], bfr[2];
            #pragma unroll
            for (int mf = 0; mf < 2; ++mf)
                af[mf] = *(const bf16x8*)(kT + (mf * 16 + lm) * 264 + sb + koff);
            #pragma unroll
            for (int nf = 0; nf < 2; ++nf)
                bfr[nf] = *(const bf16x8*)(vT + (nf * 16 + lm) * 264 + sb + koff);
            #pragma unroll
            for (int mf = 0; mf < 2; ++mf)
                #pragma unroll
                for (int nf = 0; nf < 2; ++nf)
                    acc[mf][nf] = MFMA16(af[mf], bfr[nf], acc[mf][nf]);
        }
    }
    #pragma unroll
    for (int mf = 0; mf < 2; ++mf)
        #pragma unroll
        for (int nf = 0; nf < 2; ++nf)
            #pragma unroll
            for (int r = 0; r < 4; ++r) {
                int d = mf * 16 + r0 + r, e = nf * 16 + lm;
                red[w * 1024 + d * 32 + e] = acc[mf][nf][r];
            }
    __syncthreads();
    #pragma unroll
    for (int i = 0; i < 4; ++i) {
        int idx = tid + i * 256;
        float s = red[idx] + red[1024 + idx] + red[2048 + idx] + red[3072 + idx];
        atomicAdd(&KVg[((size_t)(b * 8 + h)) * 1024 + idx], s);
    }
}

// ---------------- attn apply: msg[tok, he] = (Q . KV[h]) * Z ---------------
__global__ __launch_bounds__(256) void attn_apply(
    const __bf16* __restrict__ Qb, const float* __restrict__ KVg,
    const float* __restrict__ KSg, __bf16* __restrict__ Msg)
{
    const int tid = threadIdx.x, w = tid >> 6, l = tid & 63, lm = l & 15;
    const int tok0 = blockIdx.x * 64;
    const size_t b = blockIdx.y;
    __shared__ __bf16 kvT[8 * 32 * 40];   // [h][e][d], d contiguous
    __shared__ float ks_lds[256], z_lds[64 * 8];

    const float* KVb = KVg + b * 8192;
    #pragma unroll
    for (int i = 0; i < 32; ++i) {
        int idx = tid + i * 256;
        int h = idx >> 10, d = (idx >> 5) & 31, e = idx & 31;
        kvT[(h * 32 + e) * 40 + d] = (__bf16)KVb[idx];
    }
    ks_lds[tid] = KSg[b * 256 + tid];
    __syncthreads();

    const __bf16* Qbase = Qb + (b * 16384 + tok0) * (size_t)256;
    #pragma unroll
    for (int i = 0; i < 2; ++i) {
        int p = tid + i * 256;            // 0..511 -> (tok, h)
        int tok = p >> 3, h = p & 7;
        const __bf16* qr = Qbase + (size_t)tok * 256 + h * 32;
        float s = 0.f;
        #pragma unroll
        for (int j = 0; j < 4; ++j) {
            bf16x8 q8 = *(const bf16x8*)(qr + j * 8);
            #pragma unroll
            for (int t = 0; t < 8; ++t) s += (float)q8[t] * ks_lds[h * 32 + j * 8 + t];
        }
        z_lds[tok * 8 + h] = 1.f / (s + 1e-6f);
    }
    __syncthreads();

    const int koff = (l >> 4) * 8, r0 = (l >> 4) * 4;
    const f32x4 zero4 = (f32x4){0.f, 0.f, 0.f, 0.f};
    #pragma unroll
    for (int h = 0; h < 8; ++h) {
        bf16x8 af = *(const bf16x8*)(Qbase + (size_t)(w * 16 + lm) * 256 + h * 32 + koff);
        #pragma unroll
        for (int nf = 0; nf < 2; ++nf) {
            bf16x8 bv = *(const bf16x8*)(kvT + (h * 32 + nf * 16 + lm) * 40 + koff);
            f32x4 m = MFMA16(af, bv, zero4);
            #pragma unroll
            for (int r = 0; r < 4; ++r) {
                int tok = w * 16 + r0 + r;
                Msg[(b * 16384 + tok0 + tok) * (size_t)256 + h * 32 + nf * 16 + lm] =
                    (__bf16)(m[r] * z_lds[tok * 8 + h]);
            }
        }
    }
}

// ------- fused GEMM (N=256) + LayerNorm; bf16 token-major or fp32 transposed
template <bool TRANS>
__global__ __launch_bounds__(256, 2) void gemm_ln(
    const __bf16* __restrict__ Ag,   // [B*16384, K]
    const __bf16* __restrict__ Wg,   // [256, K]
    const float* __restrict__ gv, const float* __restrict__ bv,
    __bf16* __restrict__ OutB,       // [B*16384, 256]  (!TRANS)
    float* __restrict__ OutF,        // [B, 256, 16384] (TRANS)
    int K)
{
    const int tid = threadIdx.x, w = tid >> 6, l = tid & 63, lm = l & 15;
    const int tok0 = blockIdx.x * 128;
    const size_t b = blockIdx.y;
    const size_t trow = b * 16384 + tok0;

    __shared__ __bf16 Alds[128 * 32];
    __shared__ __bf16 Wlds[256 * 32];
    __shared__ float red1[4 * 128], red2[4 * 128], mu_lds[128], rs_lds[128];
    __shared__ float g_lds[256], b_lds[256];
    g_lds[tid] = gv[tid];
    b_lds[tid] = bv[tid];

    f32x4 acc[8][4];
    #pragma unroll
    for (int i = 0; i < 8; ++i)
        #pragma unroll
        for (int j = 0; j < 4; ++j) acc[i][j] = (f32x4){0.f, 0.f, 0.f, 0.f};

    const int srow = tid >> 2, scol = (tid & 3) * 8;
    const int koff = (l >> 4) * 8, wn = w * 64, wbase = w * 512;

    for (int ks = 0; ks < K; ks += 32) {
        __syncthreads();
        gll16(Ag + (trow + srow) * K + ks + scol,        Alds + wbase);
        gll16(Ag + (trow + 64 + srow) * K + ks + scol,   Alds + 2048 + wbase);
        #pragma unroll
        for (int c = 0; c < 4; ++c)
            gll16(Wg + (size_t)(c * 64 + srow) * K + ks + scol, Wlds + c * 2048 + wbase);
        __syncthreads();
        bf16x8 af[8], wf[4];
        #pragma unroll
        for (int mf = 0; mf < 8; ++mf)
            af[mf] = *(const bf16x8*)(Alds + (mf * 16 + lm) * 32 + koff);
        #pragma unroll
        for (int nf = 0; nf < 4; ++nf)
            wf[nf] = *(const bf16x8*)(Wlds + (wn + nf * 16 + lm) * 32 + koff);
        #pragma unroll
        for (int mf = 0; mf < 8; ++mf)
            #pragma unroll
            for (int nf = 0; nf < 4; ++nf)
                acc[mf][nf] = MFMA16(af[mf], wf[nf], acc[mf][nf]);
    }

    const int r0 = (l >> 4) * 4;
    // per-token partial sums over this wave's 64 channels
    #pragma unroll
    for (int mf = 0; mf < 8; ++mf) {
        #pragma unroll
        for (int r = 0; r < 4; ++r) {
            float s1 = 0.f, s2 = 0.f;
            #pragma unroll
            for (int nf = 0; nf < 4; ++nf) { float v = acc[mf][nf][r]; s1 += v; s2 += v * v; }
            #pragma unroll
            for (int m = 1; m < 16; m <<= 1) { s1 += __shfl_xor(s1, m, 64); s2 += __shfl_xor(s2, m, 64); }
            if (lm == 0) {
                red1[w * 128 + mf * 16 + r0 + r] = s1;
                red2[w * 128 + mf * 16 + r0 + r] = s2;
            }
        }
    }
    __syncthreads();
    if (tid < 128) {
        float s1 = red1[tid] + red1[128 + tid] + red1[256 + tid] + red1[384 + tid];
        float s2 = red2[tid] + red2[128 + tid] + red2[256 + tid] + red2[384 + tid];
        float mu = s1 * (1.f / 256.f);
        mu_lds[tid] = mu;
        rs_lds[tid] = rsqrtf(s2 * (1.f / 256.f) - mu * mu + 1e-5f);
    }
    __syncthreads();

    if (TRANS) {
        #pragma unroll
        for (int mf = 0; mf < 8; ++mf) {
            #pragma unroll
            for (int nf = 0; nf < 4; ++nf) {
                int ch = wn + nf * 16 + lm;
                int tl = mf * 16 + r0;
                float4 v;
                v.x = (acc[mf][nf][0] - mu_lds[tl + 0]) * rs_lds[tl + 0] * g_lds[ch] + b_lds[ch];
                v.y = (acc[mf][nf][1] - mu_lds[tl + 1]) * rs_lds[tl + 1] * g_lds[ch] + b_lds[ch];
                v.z = (acc[mf][nf][2] - mu_lds[tl + 2]) * rs_lds[tl + 2] * g_lds[ch] + b_lds[ch];
                v.w = (acc[mf][nf][3] - mu_lds[tl + 3]) * rs_lds[tl + 3] * g_lds[ch] + b_lds[ch];
                *(float4*)(OutF + (b * 256 + ch) * (size_t)16384 + tok0 + tl) = v;
            }
        }
    } else {
        #pragma unroll
        for (int mf = 0; mf < 8; ++mf) {
            #pragma unroll
            for (int nf = 0; nf < 4; ++nf) {
                int ch = wn + nf * 16 + lm;
                #pragma unroll
                for (int r = 0; r < 4; ++r) {
                    int tl = mf * 16 + r0 + r;
                    float y = (acc[mf][nf][r] - mu_lds[tl]) * rs_lds[tl] * g_lds[ch] + b_lds[ch];
                    OutB[(trow + tl) * (size_t)256 + ch] = (__bf16)y;
                }
            }
        }
    }
}

// ---------------------------------------------------------------------------
extern "C" void kernel_launch(void* const* d_in, const int* in_sizes, int n_in,
                              void* d_out, int out_size, void* d_ws, size_t ws_size,
                              hipStream_t stream) {
    const float* feat1   = (const float*)d_in[0];
    const float* feat2   = (const float*)d_in[2];
    const float* xyz2    = (const float*)d_in[3];
    const float* pos_w1  = (const float*)d_in[4];
    const float* pos_b1  = (const float*)d_in[5];
    const float* pos_w2  = (const float*)d_in[6];
    const float* pos_b2  = (const float*)d_in[7];
    const float* q_w     = (const float*)d_in[8];
    const float* k_w     = (const float*)d_in[9];
    const float* v_w     = (const float*)d_in[10];
    const float* merge_w = (const float*)d_in[11];
    const float* mlp_w1  = (const float*)d_in[12];
    const float* mlp_w2  = (const float*)d_in[13];
    const float* ln1_g   = (const float*)d_in[14];
    const float* ln1_b   = (const float*)d_in[15];
    const float* ln2_g   = (const float*)d_in[16];
    const float* ln2_b   = (const float*)d_in[17];
    float* outp = (float*)d_out;

    char* ws = (char*)d_ws;
    size_t off = 0;
    auto alloc = [&](size_t bytes) { char* p = ws + off; off += (bytes + 255) & ~(size_t)255; return p; };
    const size_t ACT = (size_t)4 * 16384 * 256 * 2;
    __bf16* WQ  = (__bf16*)alloc(65536 * 2);
    __bf16* WK  = (__bf16*)alloc(65536 * 2);
    __bf16* WV  = (__bf16*)alloc(65536 * 2);
    __bf16* WM  = (__bf16*)alloc(65536 * 2);
    __bf16* WP2 = (__bf16*)alloc(65536 * 2);
    __bf16* W1  = (__bf16*)alloc(262144 * 2);
    __bf16* W2  = (__bf16*)alloc(131072 * 2);
    float*  KV  = (float*)alloc(4 * 8 * 32 * 32 * 4);  // zeroed each call (with KS)
    float*  KS  = (float*)alloc(4 * 256 * 4);
    __bf16* F1T = (__bf16*)alloc(ACT);
    __bf16* HID = (__bf16*)alloc(ACT);   // reused (with F2T) as H1 [tok,512]
    __bf16* F2T = (__bf16*)alloc(ACT);   // reused as MSGRAW after K-gemm
    __bf16* F2P = (__bf16*)alloc(ACT);   // reused as MSG1 after V-gemm
    __bf16* KB  = (__bf16*)alloc(ACT);
    __bf16* VB  = (__bf16*)alloc(ACT);
    __bf16* QB  = (__bf16*)alloc(ACT);
    __bf16* H1     = HID;
    __bf16* MSGRAW = F2T;
    __bf16* MSG1   = F2P;
    if (ws_size < off) return;

    // 1. weights -> bf16, zero KV/Ksum
    prep_weights_kernel<<<2948, 256, 0, stream>>>(q_w, k_w, v_w, merge_w, pos_w2,
                                                  mlp_w1, mlp_w2,
                                                  WQ, WK, WV, WM, WP2, W1, W2, KV);
    // 2. pos-MLP hidden
    pos_hidden_kernel<<<8192, 256, 0, stream>>>(xyz2, pos_w1, pos_b1, HID);
    // 3/4. transpose feat1, feat2 to token-major bf16
    transpose_cast_kernel<<<dim3(256, 4, 4), 256, 0, stream>>>(feat1, F1T);
    transpose_cast_kernel<<<dim3(256, 4, 4), 256, 0, stream>>>(feat2, F2T);
    // 5. F2P = f2 + (hidden @ pos_w2^T + pos_b2)
    gemm_tok<EPI_ADDB, false><<<dim3(128, 2, 4), 256, 0, stream>>>(WP2, HID, nullptr, F2P, pos_b2, F2T, nullptr, 256, 256);
    // 6. K = elu(f2 @ k_w^T) + 1, fused Ksum
    gemm_tok<EPI_ELU_KSUM, false><<<dim3(128, 2, 4), 256, 0, stream>>>(WK, F2T, nullptr, KB, nullptr, nullptr, KS, 256, 256);
    // 7. v = f2p @ v_w^T
    gemm_tok<EPI_STORE, false><<<dim3(128, 2, 4), 256, 0, stream>>>(WV, F2P, nullptr, VB, nullptr, nullptr, nullptr, 256, 256);
    // 8. Q = elu(f1 @ q_w^T) + 1
    gemm_tok<EPI_ELU, false><<<dim3(128, 2, 4), 256, 0, stream>>>(WQ, F1T, nullptr, QB, nullptr, nullptr, nullptr, 256, 256);
    // 9. KV
    kv_kernel<<<dim3(16, 8, 4), 256, 0, stream>>>(KB, VB, KV);
    // 10. msg = (Q . KV) * Z  (raw, pre-merge)
    attn_apply<<<dim3(256, 4), 256, 0, stream>>>(QB, KV, KS, MSGRAW);
    // 11. msg1 = LN1(msg @ merge_w^T)
    gemm_ln<false><<<dim3(128, 4), 256, 0, stream>>>(MSGRAW, WM, ln1_g, ln1_b, MSG1, nullptr, 256);
    // 12. h1 = relu([f1, msg1] @ mlp_w1^T)
    gemm_tok<EPI_RELU, true><<<dim3(128, 4, 4), 256, 0, stream>>>(W1, F1T, MSG1, H1, nullptr, nullptr, nullptr, 512, 512);
    // 13. out = LN2(h1 @ mlp_w2^T), stored [B, 256, N] fp32
    gemm_ln<true><<<dim3(128, 4), 256, 0, stream>>>(H1, W2, ln2_g, ln2_b, nullptr, outp, 512);
    (void)in_sizes; (void)n_in; (void)out_size;
}